// Round 1
// baseline (516.375 us; speedup 1.0000x reference)
//
#include <hip/hip_runtime.h>
#include <hip/hip_bf16.h>
#include <stdint.h>

#define B_ROWS 16384
#define NVARS 64
#define LAG 16
#define H1 64
#define H2 1024
#define KDIM (NVARS * H1)   // 4096

typedef __attribute__((ext_vector_type(8))) short short8;
typedef __attribute__((ext_vector_type(4))) float f32x4;

typedef __attribute__((address_space(3))) uint8_t lds_u8;
typedef const __attribute__((address_space(1))) uint8_t glob_u8;

__device__ __forceinline__ void gload_lds16(const void* g, void* l) {
    __builtin_amdgcn_global_load_lds((glob_u8*)g, (lds_u8*)l, 16, 0, 0);
}

// ---------------------------------------------------------------------------
// Kernel A: W3 [4096][1024] f32  ->  W3T [1024][4096] bf16 (tiled transpose)
// ---------------------------------------------------------------------------
__global__ __launch_bounds__(256) void convert_w3t_kernel(
    const float* __restrict__ w3, __hip_bfloat16* __restrict__ w3t) {
    __shared__ float tile[64][65];
    const int bx = blockIdx.x;          // 64 k-tiles x 16 n-tiles
    const int k0 = (bx >> 4) * 64;
    const int n0 = (bx & 15) * 64;
    const int t = threadIdx.x;
    const int c = t & 63, r0 = t >> 6;
#pragma unroll
    for (int i = 0; i < 16; i++) {
        int r = r0 + i * 4;
        tile[r][c] = w3[(size_t)(k0 + r) * H2 + n0 + c];
    }
    __syncthreads();
#pragma unroll
    for (int i = 0; i < 16; i++) {
        int nr = r0 + i * 4;
        w3t[(size_t)(n0 + nr) * KDIM + k0 + c] = __float2bfloat16(tile[c][nr]);
    }
}

// ---------------------------------------------------------------------------
// Kernel B: per-variable 2-layer subnet (f32), writes agg = h2*imp as bf16
// grid: 64 vars * 256 row-tiles (64 rows each); block 256
// ---------------------------------------------------------------------------
__global__ __launch_bounds__(256) void subnets_kernel(
    const float* __restrict__ inputs, const float* __restrict__ W1,
    const float* __restrict__ b1, const float* __restrict__ W2,
    const float* __restrict__ b2, const float* __restrict__ imp,
    __hip_bfloat16* __restrict__ agg) {
    const int bid = blockIdx.x;
    const int v = bid >> 8;        // 0..63
    const int tile = bid & 255;    // 0..255
    const int b0 = tile * 64;
    const int t = threadIdx.x;

    __shared__ float w1s[LAG * H1];   // [l][h]
    __shared__ float w2s[H1 * H1];    // [h][k]
    __shared__ float xs[64 * LAG];    // [row][l]
    __shared__ float h1s[64 * H1];    // [row][h]
    __shared__ float b1s[H1], b2s[H1];

    const float* w1g = W1 + (size_t)v * LAG * H1;
#pragma unroll
    for (int i = 0; i < 4; i++) w1s[t + i * 256] = w1g[t + i * 256];
    const float* w2g = W2 + (size_t)v * H1 * H1;
#pragma unroll
    for (int i = 0; i < 16; i++) w2s[t + i * 256] = w2g[t + i * 256];
    if (t < 64) { b1s[t] = b1[v * H1 + t]; b2s[t] = b2[v * H1 + t]; }
    {
        int row = t >> 2, seg = t & 3;
        const float4* src =
            (const float4*)(inputs + (size_t)(b0 + row) * (NVARS * LAG) + v * LAG + seg * 4);
        *(float4*)&xs[row * LAG + seg * 4] = *src;
    }
    __syncthreads();

    const int col = t & 63;   // output unit
    const int wv = t >> 6;    // wave id -> rows wv*16 .. wv*16+15

    // layer 1: h1 = relu(x @ W1 + b1), 4 rows at a time for ILP
#pragma unroll
    for (int i = 0; i < 16; i += 4) {
        int r = wv * 16 + i;
        float s0 = b1s[col], s1 = b1s[col], s2 = b1s[col], s3 = b1s[col];
#pragma unroll
        for (int l = 0; l < LAG; l++) {
            float w = w1s[l * H1 + col];
            s0 += xs[(r + 0) * LAG + l] * w;
            s1 += xs[(r + 1) * LAG + l] * w;
            s2 += xs[(r + 2) * LAG + l] * w;
            s3 += xs[(r + 3) * LAG + l] * w;
        }
        h1s[(r + 0) * H1 + col] = fmaxf(s0, 0.f);
        h1s[(r + 1) * H1 + col] = fmaxf(s1, 0.f);
        h1s[(r + 2) * H1 + col] = fmaxf(s2, 0.f);
        h1s[(r + 3) * H1 + col] = fmaxf(s3, 0.f);
    }
    __syncthreads();

    const float impv = imp[v];
    // layer 2: agg = relu(h1 @ W2 + b2) * imp[v]
#pragma unroll
    for (int i = 0; i < 16; i += 4) {
        int r = wv * 16 + i;
        float s0 = b2s[col], s1 = b2s[col], s2 = b2s[col], s3 = b2s[col];
#pragma unroll
        for (int k = 0; k < H1; k++) {
            float w = w2s[k * H1 + col];
            s0 += h1s[(r + 0) * H1 + k] * w;
            s1 += h1s[(r + 1) * H1 + k] * w;
            s2 += h1s[(r + 2) * H1 + k] * w;
            s3 += h1s[(r + 3) * H1 + k] * w;
        }
        agg[(size_t)(b0 + r + 0) * KDIM + v * H1 + col] = __float2bfloat16(fmaxf(s0, 0.f) * impv);
        agg[(size_t)(b0 + r + 1) * KDIM + v * H1 + col] = __float2bfloat16(fmaxf(s1, 0.f) * impv);
        agg[(size_t)(b0 + r + 2) * KDIM + v * H1 + col] = __float2bfloat16(fmaxf(s2, 0.f) * impv);
        agg[(size_t)(b0 + r + 3) * KDIM + v * H1 + col] = __float2bfloat16(fmaxf(s3, 0.f) * impv);
    }
}

// ---------------------------------------------------------------------------
// Kernel C: relu3 = relu(agg @ W3 + b3)   [16384,4096]x[4096,1024]
// m97-style 128x128 bf16 MFMA tile, BK=32, 4 waves (2x2), global_load_lds.
// ---------------------------------------------------------------------------
#define BM 128
#define BN 128
#define BK 32

__global__ __launch_bounds__(256) void gemm3_kernel(
    const __hip_bfloat16* __restrict__ agg,   // [16384][4096]
    const __hip_bfloat16* __restrict__ w3t,   // [1024][4096]
    const float* __restrict__ b3, float* __restrict__ relu3) {
    const int bid = blockIdx.x;
    const int nTilesN = H2 / BN;              // 8
    const int brow = (bid / nTilesN) * BM;
    const int bcol = (bid % nTilesN) * BN;
    const int t = threadIdx.x;
    const int lane = t & 63;
    const int wave = t >> 6;
    const int wm = wave >> 1, wn = wave & 1;  // 2x2 wave grid, 64x64 each

    __shared__ __hip_bfloat16 As[BM * BK];    // [128][32] linear
    __shared__ __hip_bfloat16 Bs[BN * BK];

    f32x4 acc[4][4];
#pragma unroll
    for (int m = 0; m < 4; m++)
#pragma unroll
        for (int n = 0; n < 4; n++) acc[m][n] = (f32x4){0.f, 0.f, 0.f, 0.f};

    const int c0 = t, c1 = t + 256;           // 16B chunks (512 per tile)
    const int row0 = c0 >> 2, seg0 = c0 & 3;
    const int row1 = c1 >> 2, seg1 = c1 & 3;

    for (int kt = 0; kt < KDIM; kt += BK) {
        __syncthreads();
        gload_lds16(agg + (size_t)(brow + row0) * KDIM + kt + seg0 * 8, (char*)As + c0 * 16);
        gload_lds16(agg + (size_t)(brow + row1) * KDIM + kt + seg1 * 8, (char*)As + c1 * 16);
        gload_lds16(w3t + (size_t)(bcol + row0) * KDIM + kt + seg0 * 8, (char*)Bs + c0 * 16);
        gload_lds16(w3t + (size_t)(bcol + row1) * KDIM + kt + seg1 * 8, (char*)Bs + c1 * 16);
        __syncthreads();

        short8 af[4], bfr[4];
#pragma unroll
        for (int m = 0; m < 4; m++)
            af[m] = *(const short8*)&As[(wm * 64 + m * 16 + (lane & 15)) * BK + (lane >> 4) * 8];
#pragma unroll
        for (int n = 0; n < 4; n++)
            bfr[n] = *(const short8*)&Bs[(wn * 64 + n * 16 + (lane & 15)) * BK + (lane >> 4) * 8];
#pragma unroll
        for (int m = 0; m < 4; m++)
#pragma unroll
            for (int n = 0; n < 4; n++)
                acc[m][n] = __builtin_amdgcn_mfma_f32_16x16x32_bf16(af[m], bfr[n], acc[m][n], 0, 0, 0);
    }

    // epilogue: D[row=(lane>>4)*4+r][col=lane&15] per 16x16 fragment
#pragma unroll
    for (int m = 0; m < 4; m++) {
#pragma unroll
        for (int n = 0; n < 4; n++) {
            int row = brow + wm * 64 + m * 16 + (lane >> 4) * 4;
            int col = bcol + wn * 64 + n * 16 + (lane & 15);
            float bias = b3[col];
#pragma unroll
            for (int r = 0; r < 4; r++) {
                relu3[(size_t)(row + r) * H2 + col] = fmaxf(acc[m][n][r] + bias, 0.f);
            }
        }
    }
}

// ---------------------------------------------------------------------------
// Kernel D: out[b] = relu3[b,:] . W4 + b4   (one wave per row)
// ---------------------------------------------------------------------------
__global__ __launch_bounds__(256) void out_kernel(
    const float* __restrict__ relu3, const float* __restrict__ W4,
    const float* __restrict__ b4, float* __restrict__ out) {
    const int t = threadIdx.x;
    const int lane = t & 63, wv = t >> 6;
    const int row = blockIdx.x * 4 + wv;
    const float* rp = relu3 + (size_t)row * H2;
    float acc = 0.f;
#pragma unroll
    for (int j = 0; j < 16; j++) {
        int idx = j * 64 + lane;
        acc += rp[idx] * W4[idx];
    }
#pragma unroll
    for (int off = 32; off > 0; off >>= 1) acc += __shfl_down(acc, off, 64);
    if (lane == 0) out[row] = acc + b4[0];
}

// ---------------------------------------------------------------------------
extern "C" void kernel_launch(void* const* d_in, const int* in_sizes, int n_in,
                              void* d_out, int out_size, void* d_ws, size_t ws_size,
                              hipStream_t stream) {
    const float* inputs = (const float*)d_in[0];
    const float* W1 = (const float*)d_in[1];
    const float* b1 = (const float*)d_in[2];
    const float* W2 = (const float*)d_in[3];
    const float* b2 = (const float*)d_in[4];
    const float* imp = (const float*)d_in[5];
    const float* W3 = (const float*)d_in[6];
    const float* b3 = (const float*)d_in[7];
    const float* W4 = (const float*)d_in[8];
    const float* b4 = (const float*)d_in[9];
    float* out = (float*)d_out;

    char* ws = (char*)d_ws;
    const size_t agg_bytes = (size_t)B_ROWS * KDIM * 2;    // 134 MB
    const size_t w3t_bytes = (size_t)H2 * KDIM * 2;        // 8.4 MB
    __hip_bfloat16* agg = (__hip_bfloat16*)ws;
    __hip_bfloat16* w3t = (__hip_bfloat16*)(ws + agg_bytes);
    float* relu3 = (float*)(ws + agg_bytes + w3t_bytes);   // 67 MB

    hipLaunchKernelGGL(convert_w3t_kernel, dim3(1024), dim3(256), 0, stream, W3, w3t);
    hipLaunchKernelGGL(subnets_kernel, dim3(16384), dim3(256), 0, stream,
                       inputs, W1, b1, W2, b2, imp, agg);
    hipLaunchKernelGGL(gemm3_kernel, dim3((B_ROWS / BM) * (H2 / BN)), dim3(256), 0, stream,
                       agg, w3t, b3, relu3);
    hipLaunchKernelGGL(out_kernel, dim3(B_ROWS / 4), dim3(256), 0, stream,
                       relu3, W4, b4, out);
}

// Round 2
// 281.969 us; speedup vs baseline: 1.8313x; 1.8313x over previous
//
#include <hip/hip_runtime.h>
#include <hip/hip_bf16.h>
#include <stdint.h>

#define B_ROWS 16384
#define NVARS 64
#define LAG 16
#define H1 64
#define H2 1024
#define KDIM (NVARS * H1)   // 4096

typedef __attribute__((ext_vector_type(8))) short short8;
typedef __attribute__((ext_vector_type(4))) short short4v;
typedef __attribute__((ext_vector_type(4))) float f32x4;

typedef __attribute__((address_space(3))) uint8_t lds_u8;
typedef const __attribute__((address_space(1))) uint8_t glob_u8;

__device__ __forceinline__ void gload_lds16(const void* g, void* l) {
    __builtin_amdgcn_global_load_lds((glob_u8*)g, (lds_u8*)l, 16, 0, 0);
}

__device__ __forceinline__ short f2bf_s(float x) {
    __hip_bfloat16 h = __float2bfloat16(x);
    return *(short*)&h;
}
__device__ __forceinline__ float bf_s2f(short s) {
    __hip_bfloat16 h = *(__hip_bfloat16*)&s;
    return __bfloat162float(h);
}

// ---------------------------------------------------------------------------
// Kernel A: W3 [4096][1024] f32 -> W3T [1024][4096] bf16 (tiled transpose)
// ---------------------------------------------------------------------------
__global__ __launch_bounds__(256) void convert_w3t_kernel(
    const float* __restrict__ w3, __hip_bfloat16* __restrict__ w3t) {
    __shared__ float tile[64][65];
    const int bx = blockIdx.x;
    const int k0 = (bx >> 4) * 64;
    const int n0 = (bx & 15) * 64;
    const int t = threadIdx.x;
    const int c = t & 63, r0 = t >> 6;
#pragma unroll
    for (int i = 0; i < 16; i++) {
        int r = r0 + i * 4;
        tile[r][c] = w3[(size_t)(k0 + r) * H2 + n0 + c];
    }
    __syncthreads();
#pragma unroll
    for (int i = 0; i < 16; i++) {
        int nr = r0 + i * 4;
        w3t[(size_t)(n0 + nr) * KDIM + k0 + c] = __float2bfloat16(tile[c][nr]);
    }
}

// ---------------------------------------------------------------------------
// Kernel A2: build hi/lo B-operand (transposed, padded) tiles for W1, W2.
// w1bh/w1bl: [64 vars][64 cols][40]  (k<32 valid; B1T[col][k]=Whi[k%16][col],
//                                     B1loT[col][k]= k<16 ? Wlo[k][col] : 0)
// w2bh/w2bl: [64 vars][64 cols][72]  (k<64 valid; = W2hi/lo[k][col])
// ---------------------------------------------------------------------------
__global__ __launch_bounds__(256) void prep_w12_kernel(
    const float* __restrict__ W1, const float* __restrict__ W2,
    short* __restrict__ w1bh, short* __restrict__ w1bl,
    short* __restrict__ w2bh, short* __restrict__ w2bl) {
    const int v = blockIdx.x, t = threadIdx.x;
    for (int idx = t; idx < 64 * 32; idx += 256) {
        int col = idx >> 5, k = idx & 31;
        float wv = W1[((size_t)v * LAG + (k & 15)) * H1 + col];
        short hi = f2bf_s(wv);
        w1bh[((size_t)v * 64 + col) * 40 + k] = hi;
        w1bl[((size_t)v * 64 + col) * 40 + k] = (k < 16) ? f2bf_s(wv - bf_s2f(hi)) : (short)0;
    }
    for (int idx = t; idx < 64 * 64; idx += 256) {
        int col = idx >> 6, k = idx & 63;
        float wv = W2[((size_t)v * H1 + k) * H1 + col];
        short hi = f2bf_s(wv);
        w2bh[((size_t)v * 64 + col) * 72 + k] = hi;
        w2bl[((size_t)v * 64 + col) * 72 + k] = f2bf_s(wv - bf_s2f(hi));
    }
}

// ---------------------------------------------------------------------------
// Kernel A3: out[i] = b4[0]  (gemm3 atomically accumulates the W4 dot on top)
// ---------------------------------------------------------------------------
__global__ __launch_bounds__(256) void out_init_kernel(
    const float* __restrict__ b4, float* __restrict__ out) {
    out[blockIdx.x * 256 + threadIdx.x] = b4[0];
}

// ---------------------------------------------------------------------------
// Kernel B: per-variable 2-layer subnet via split-bf16 MFMA.
// Block = 1 var x 128 rows; 4 waves, wave w owns rows 32w..32w+31.
// Layer1: A=[x_hi|x_lo] (K=32), 2 MFMAs/tile. Layer2: K=64 hi/lo, 6 MFMAs/tile.
// ---------------------------------------------------------------------------
__global__ __launch_bounds__(256) void subnets_mfma_kernel(
    const float* __restrict__ inputs, const float* __restrict__ b1g,
    const float* __restrict__ b2g, const float* __restrict__ impg,
    const short* __restrict__ w1bh_g, const short* __restrict__ w1bl_g,
    const short* __restrict__ w2bh_g, const short* __restrict__ w2bl_g,
    __hip_bfloat16* __restrict__ agg) {
    const int v = blockIdx.x >> 7;
    const int b0 = (blockIdx.x & 127) * 128;
    const int t = threadIdx.x;
    const int lane = t & 63, wv = t >> 6;
    const int l15 = lane & 15, g = lane >> 4;

    // LDS: [0,34816) = H [128][136] bf16 (after L1); pre-L1 same region holds
    //   xs [128][40] @0, w1bhS [64][40] @10240, w1blS @15360.
    // [34816,44032) w2bhS [64][72]; [44032,53248) w2blS.
    __shared__ __align__(16) char smem[53248];
    short* xsS   = (short*)smem;
    short* w1bhS = (short*)(smem + 10240);
    short* w1blS = (short*)(smem + 15360);
    short* Hs    = (short*)smem;
    short* w2bhS = (short*)(smem + 34816);
    short* w2blS = (short*)(smem + 44032);

    // ---- stage B-operand weight tiles (global_load_lds, 16B) ----
    for (int c = t; c < 320; c += 256) {
        gload_lds16(w1bh_g + (size_t)v * 2560 + c * 8, (char*)w1bhS + c * 16);
        gload_lds16(w1bl_g + (size_t)v * 2560 + c * 8, (char*)w1blS + c * 16);
    }
    for (int c = t; c < 576; c += 256) {
        gload_lds16(w2bh_g + (size_t)v * 4608 + c * 8, (char*)w2bhS + c * 16);
        gload_lds16(w2bl_g + (size_t)v * 4608 + c * 8, (char*)w2blS + c * 16);
    }
    // ---- stage x, split hi/lo: xs[row][k<16]=hi, [16..31]=lo ----
#pragma unroll
    for (int i = 0; i < 2; i++) {
        int idx = t + i * 256;
        int row = idx >> 2, seg = idx & 3;
        float4 x4 = *(const float4*)(inputs + (size_t)(b0 + row) * (NVARS * LAG) + v * LAG + seg * 4);
        const float* xp = (const float*)&x4;
        short4v hv, lv;
#pragma unroll
        for (int j = 0; j < 4; j++) {
            short hi = f2bf_s(xp[j]);
            hv[j] = hi;
            lv[j] = f2bf_s(xp[j] - bf_s2f(hi));
        }
        *(short4v*)&xsS[row * 40 + seg * 4] = hv;
        *(short4v*)&xsS[row * 40 + 16 + seg * 4] = lv;
    }
    __syncthreads();

    // ---- layer 1 ----
    short8 a1[2], b1hF[4], b1lF[4];
#pragma unroll
    for (int mt = 0; mt < 2; mt++)
        a1[mt] = *(const short8*)&xsS[(wv * 32 + mt * 16 + l15) * 40 + g * 8];
#pragma unroll
    for (int nt = 0; nt < 4; nt++) {
        b1hF[nt] = *(const short8*)&w1bhS[(nt * 16 + l15) * 40 + g * 8];
        b1lF[nt] = *(const short8*)&w1blS[(nt * 16 + l15) * 40 + g * 8];
    }
    f32x4 acc1[2][4];
#pragma unroll
    for (int mt = 0; mt < 2; mt++)
#pragma unroll
        for (int nt = 0; nt < 4; nt++) {
            acc1[mt][nt] = (f32x4){0.f, 0.f, 0.f, 0.f};
            acc1[mt][nt] = __builtin_amdgcn_mfma_f32_16x16x32_bf16(a1[mt], b1hF[nt], acc1[mt][nt], 0, 0, 0);
            acc1[mt][nt] = __builtin_amdgcn_mfma_f32_16x16x32_bf16(a1[mt], b1lF[nt], acc1[mt][nt], 0, 0, 0);
        }
    __syncthreads();   // all fragment reads of xs/w1 done before H overwrites them

    // ---- relu + hi/lo split -> H [128][136]: cols 0-63 hi, 64-127 lo ----
#pragma unroll
    for (int mt = 0; mt < 2; mt++)
#pragma unroll
        for (int nt = 0; nt < 4; nt++) {
            int col = nt * 16 + l15;
            float bias = b1g[v * H1 + col];
#pragma unroll
            for (int r = 0; r < 4; r++) {
                float h = fmaxf(acc1[mt][nt][r] + bias, 0.f);
                short hi = f2bf_s(h);
                short lo = f2bf_s(h - bf_s2f(hi));
                int row = wv * 32 + mt * 16 + g * 4 + r;
                Hs[row * 136 + col] = hi;
                Hs[row * 136 + 64 + col] = lo;
            }
        }
    __syncthreads();

    // ---- layer 2 ----
    short8 a2[2][4], b2hF[4][2], b2lF[4][2];
#pragma unroll
    for (int mt = 0; mt < 2; mt++)
#pragma unroll
        for (int c = 0; c < 4; c++)
            a2[mt][c] = *(const short8*)&Hs[(wv * 32 + mt * 16 + l15) * 136 + c * 32 + g * 8];
#pragma unroll
    for (int nt = 0; nt < 4; nt++)
#pragma unroll
        for (int kc = 0; kc < 2; kc++) {
            b2hF[nt][kc] = *(const short8*)&w2bhS[(nt * 16 + l15) * 72 + kc * 32 + g * 8];
            b2lF[nt][kc] = *(const short8*)&w2blS[(nt * 16 + l15) * 72 + kc * 32 + g * 8];
        }
    f32x4 acc2[2][4];
#pragma unroll
    for (int mt = 0; mt < 2; mt++)
#pragma unroll
        for (int nt = 0; nt < 4; nt++) {
            f32x4 a = (f32x4){0.f, 0.f, 0.f, 0.f};
            a = __builtin_amdgcn_mfma_f32_16x16x32_bf16(a2[mt][0], b2hF[nt][0], a, 0, 0, 0);
            a = __builtin_amdgcn_mfma_f32_16x16x32_bf16(a2[mt][1], b2hF[nt][1], a, 0, 0, 0);
            a = __builtin_amdgcn_mfma_f32_16x16x32_bf16(a2[mt][2], b2hF[nt][0], a, 0, 0, 0);
            a = __builtin_amdgcn_mfma_f32_16x16x32_bf16(a2[mt][3], b2hF[nt][1], a, 0, 0, 0);
            a = __builtin_amdgcn_mfma_f32_16x16x32_bf16(a2[mt][0], b2lF[nt][0], a, 0, 0, 0);
            a = __builtin_amdgcn_mfma_f32_16x16x32_bf16(a2[mt][1], b2lF[nt][1], a, 0, 0, 0);
            acc2[mt][nt] = a;
        }

    // ---- epilogue: agg = relu(.+b2)*imp as bf16 ----
    const float impv = impg[v];
#pragma unroll
    for (int mt = 0; mt < 2; mt++)
#pragma unroll
        for (int nt = 0; nt < 4; nt++) {
            int col = nt * 16 + l15;
            float bias = b2g[v * H1 + col];
#pragma unroll
            for (int r = 0; r < 4; r++) {
                float o = fmaxf(acc2[mt][nt][r] + bias, 0.f) * impv;
                int row = b0 + wv * 32 + mt * 16 + g * 4 + r;
                agg[(size_t)row * KDIM + v * H1 + col] = __float2bfloat16(o);
            }
        }
}

// ---------------------------------------------------------------------------
// Kernel C: relu(agg @ W3 + b3) fused with the W4 dot -> atomicAdd into out.
// ---------------------------------------------------------------------------
#define BM 128
#define BN 128
#define BK 32

__global__ __launch_bounds__(256) void gemm3_kernel(
    const __hip_bfloat16* __restrict__ agg,   // [16384][4096]
    const __hip_bfloat16* __restrict__ w3t,   // [1024][4096]
    const float* __restrict__ b3, const float* __restrict__ W4,
    float* __restrict__ out) {
    const int bid = blockIdx.x;
    const int nTilesN = H2 / BN;              // 8
    const int brow = (bid / nTilesN) * BM;
    const int bcol = (bid % nTilesN) * BN;
    const int t = threadIdx.x;
    const int lane = t & 63;
    const int wave = t >> 6;
    const int wm = wave >> 1, wn = wave & 1;
    const int l15 = lane & 15, g = lane >> 4;

    __shared__ __hip_bfloat16 As[BM * BK];
    __shared__ __hip_bfloat16 Bs[BN * BK];

    f32x4 acc[4][4];
#pragma unroll
    for (int m = 0; m < 4; m++)
#pragma unroll
        for (int n = 0; n < 4; n++) acc[m][n] = (f32x4){0.f, 0.f, 0.f, 0.f};

    const int c0 = t, c1 = t + 256;
    const int row0 = c0 >> 2, seg0 = c0 & 3;
    const int row1 = c1 >> 2, seg1 = c1 & 3;

    for (int kt = 0; kt < KDIM; kt += BK) {
        __syncthreads();
        gload_lds16(agg + (size_t)(brow + row0) * KDIM + kt + seg0 * 8, (char*)As + c0 * 16);
        gload_lds16(agg + (size_t)(brow + row1) * KDIM + kt + seg1 * 8, (char*)As + c1 * 16);
        gload_lds16(w3t + (size_t)(bcol + row0) * KDIM + kt + seg0 * 8, (char*)Bs + c0 * 16);
        gload_lds16(w3t + (size_t)(bcol + row1) * KDIM + kt + seg1 * 8, (char*)Bs + c1 * 16);
        __syncthreads();

        short8 af[4], bfr[4];
#pragma unroll
        for (int m = 0; m < 4; m++)
            af[m] = *(const short8*)&As[(wm * 64 + m * 16 + l15) * BK + g * 8];
#pragma unroll
        for (int n = 0; n < 4; n++)
            bfr[n] = *(const short8*)&Bs[(wn * 64 + n * 16 + l15) * BK + g * 8];
#pragma unroll
        for (int m = 0; m < 4; m++)
#pragma unroll
            for (int n = 0; n < 4; n++)
                acc[m][n] = __builtin_amdgcn_mfma_f32_16x16x32_bf16(af[m], bfr[n], acc[m][n], 0, 0, 0);
    }

    // epilogue: bias+relu, dot with W4, 16-lane shfl reduce, atomicAdd per row
    float bias[4], w4v[4];
#pragma unroll
    for (int n = 0; n < 4; n++) {
        int col = bcol + wn * 64 + n * 16 + l15;
        bias[n] = b3[col];
        w4v[n] = W4[col];
    }
#pragma unroll
    for (int m = 0; m < 4; m++) {
        float pr0 = 0.f, pr1 = 0.f, pr2 = 0.f, pr3 = 0.f;
#pragma unroll
        for (int n = 0; n < 4; n++) {
            pr0 += fmaxf(acc[m][n][0] + bias[n], 0.f) * w4v[n];
            pr1 += fmaxf(acc[m][n][1] + bias[n], 0.f) * w4v[n];
            pr2 += fmaxf(acc[m][n][2] + bias[n], 0.f) * w4v[n];
            pr3 += fmaxf(acc[m][n][3] + bias[n], 0.f) * w4v[n];
        }
#pragma unroll
        for (int mask = 1; mask < 16; mask <<= 1) {
            pr0 += __shfl_xor(pr0, mask, 64);
            pr1 += __shfl_xor(pr1, mask, 64);
            pr2 += __shfl_xor(pr2, mask, 64);
            pr3 += __shfl_xor(pr3, mask, 64);
        }
        if (l15 == 0) {
            int row = brow + wm * 64 + m * 16 + g * 4;
            atomicAdd(&out[row + 0], pr0);
            atomicAdd(&out[row + 1], pr1);
            atomicAdd(&out[row + 2], pr2);
            atomicAdd(&out[row + 3], pr3);
        }
    }
}

// ---------------------------------------------------------------------------
extern "C" void kernel_launch(void* const* d_in, const int* in_sizes, int n_in,
                              void* d_out, int out_size, void* d_ws, size_t ws_size,
                              hipStream_t stream) {
    const float* inputs = (const float*)d_in[0];
    const float* W1 = (const float*)d_in[1];
    const float* b1 = (const float*)d_in[2];
    const float* W2 = (const float*)d_in[3];
    const float* b2 = (const float*)d_in[4];
    const float* imp = (const float*)d_in[5];
    const float* W3 = (const float*)d_in[6];
    const float* b3 = (const float*)d_in[7];
    const float* W4 = (const float*)d_in[8];
    const float* b4 = (const float*)d_in[9];
    float* out = (float*)d_out;

    char* ws = (char*)d_ws;
    const size_t agg_bytes  = (size_t)B_ROWS * KDIM * 2;        // 134,217,728
    const size_t w3t_bytes  = (size_t)H2 * KDIM * 2;            // 8,388,608
    const size_t w1b_bytes  = (size_t)NVARS * 64 * 40 * 2;      // 327,680
    const size_t w2b_bytes  = (size_t)NVARS * 64 * 72 * 2;      // 589,824

    __hip_bfloat16* agg = (__hip_bfloat16*)ws;
    __hip_bfloat16* w3t = (__hip_bfloat16*)(ws + agg_bytes);
    short* w1bh = (short*)(ws + agg_bytes + w3t_bytes);
    short* w1bl = (short*)(ws + agg_bytes + w3t_bytes + w1b_bytes);
    short* w2bh = (short*)(ws + agg_bytes + w3t_bytes + 2 * w1b_bytes);
    short* w2bl = (short*)(ws + agg_bytes + w3t_bytes + 2 * w1b_bytes + w2b_bytes);

    hipLaunchKernelGGL(convert_w3t_kernel, dim3(1024), dim3(256), 0, stream, W3, w3t);
    hipLaunchKernelGGL(prep_w12_kernel, dim3(NVARS), dim3(256), 0, stream,
                       W1, W2, w1bh, w1bl, w2bh, w2bl);
    hipLaunchKernelGGL(out_init_kernel, dim3(B_ROWS / 256), dim3(256), 0, stream, b4, out);
    hipLaunchKernelGGL(subnets_mfma_kernel, dim3(NVARS * (B_ROWS / 128)), dim3(256), 0, stream,
                       inputs, b1, b2, imp, w1bh, w1bl, w2bh, w2bl, agg);
    hipLaunchKernelGGL(gemm3_kernel, dim3((B_ROWS / BM) * (H2 / BN)), dim3(256), 0, stream,
                       agg, w3t, b3, W4, out);
}

// Round 3
// 222.144 us; speedup vs baseline: 2.3245x; 1.2693x over previous
//
#include <hip/hip_runtime.h>
#include <hip/hip_bf16.h>
#include <stdint.h>

#define B_ROWS 16384
#define NVARS 64
#define LAG 16
#define H1 64
#define H2 1024
#define KDIM (NVARS * H1)   // 4096

typedef __attribute__((ext_vector_type(8))) short short8;
typedef __attribute__((ext_vector_type(4))) short short4v;
typedef __attribute__((ext_vector_type(4))) float f32x4;

typedef __attribute__((address_space(3))) uint8_t lds_u8;
typedef const __attribute__((address_space(1))) uint8_t glob_u8;

__device__ __forceinline__ void gload_lds16(const void* g, void* l) {
    __builtin_amdgcn_global_load_lds((glob_u8*)g, (lds_u8*)l, 16, 0, 0);
}

__device__ __forceinline__ short f2bf_s(float x) {
    __hip_bfloat16 h = __float2bfloat16(x);
    return *(short*)&h;
}
__device__ __forceinline__ float bf_s2f(short s) {
    __hip_bfloat16 h = *(__hip_bfloat16*)&s;
    return __bfloat162float(h);
}

// ---------------------------------------------------------------------------
// Kernel A: W3 [4096][1024] f32 -> W3T [1024][4096] bf16 (tiled transpose)
// ---------------------------------------------------------------------------
__global__ __launch_bounds__(256) void convert_w3t_kernel(
    const float* __restrict__ w3, __hip_bfloat16* __restrict__ w3t) {
    __shared__ float tile[64][65];
    const int bx = blockIdx.x;
    const int k0 = (bx >> 4) * 64;
    const int n0 = (bx & 15) * 64;
    const int t = threadIdx.x;
    const int c = t & 63, r0 = t >> 6;
#pragma unroll
    for (int i = 0; i < 16; i++) {
        int r = r0 + i * 4;
        tile[r][c] = w3[(size_t)(k0 + r) * H2 + n0 + c];
    }
    __syncthreads();
#pragma unroll
    for (int i = 0; i < 16; i++) {
        int nr = r0 + i * 4;
        w3t[(size_t)(n0 + nr) * KDIM + k0 + c] = __float2bfloat16(tile[c][nr]);
    }
}

// ---------------------------------------------------------------------------
// Kernel A2: build hi/lo B-operand (transposed, padded) tiles for W1, W2.
// ---------------------------------------------------------------------------
__global__ __launch_bounds__(256) void prep_w12_kernel(
    const float* __restrict__ W1, const float* __restrict__ W2,
    short* __restrict__ w1bh, short* __restrict__ w1bl,
    short* __restrict__ w2bh, short* __restrict__ w2bl) {
    const int v = blockIdx.x, t = threadIdx.x;
    for (int idx = t; idx < 64 * 32; idx += 256) {
        int col = idx >> 5, k = idx & 31;
        float wv = W1[((size_t)v * LAG + (k & 15)) * H1 + col];
        short hi = f2bf_s(wv);
        w1bh[((size_t)v * 64 + col) * 40 + k] = hi;
        w1bl[((size_t)v * 64 + col) * 40 + k] = (k < 16) ? f2bf_s(wv - bf_s2f(hi)) : (short)0;
    }
    for (int idx = t; idx < 64 * 64; idx += 256) {
        int col = idx >> 6, k = idx & 63;
        float wv = W2[((size_t)v * H1 + k) * H1 + col];
        short hi = f2bf_s(wv);
        w2bh[((size_t)v * 64 + col) * 72 + k] = hi;
        w2bl[((size_t)v * 64 + col) * 72 + k] = f2bf_s(wv - bf_s2f(hi));
    }
}

// ---------------------------------------------------------------------------
// Kernel A3: out[i] = b4[0]  (gemm3 atomically accumulates the W4 dot on top)
// ---------------------------------------------------------------------------
__global__ __launch_bounds__(256) void out_init_kernel(
    const float* __restrict__ b4, float* __restrict__ out) {
    out[blockIdx.x * 256 + threadIdx.x] = b4[0];
}

// ---------------------------------------------------------------------------
// Kernel B: per-variable 2-layer subnet via split-bf16 MFMA (validated r2).
// ---------------------------------------------------------------------------
__global__ __launch_bounds__(256) void subnets_mfma_kernel(
    const float* __restrict__ inputs, const float* __restrict__ b1g,
    const float* __restrict__ b2g, const float* __restrict__ impg,
    const short* __restrict__ w1bh_g, const short* __restrict__ w1bl_g,
    const short* __restrict__ w2bh_g, const short* __restrict__ w2bl_g,
    __hip_bfloat16* __restrict__ agg) {
    const int v = blockIdx.x >> 7;
    const int b0 = (blockIdx.x & 127) * 128;
    const int t = threadIdx.x;
    const int lane = t & 63, wv = t >> 6;
    const int l15 = lane & 15, g = lane >> 4;

    __shared__ __align__(16) char smem[53248];
    short* xsS   = (short*)smem;
    short* w1bhS = (short*)(smem + 10240);
    short* w1blS = (short*)(smem + 15360);
    short* Hs    = (short*)smem;
    short* w2bhS = (short*)(smem + 34816);
    short* w2blS = (short*)(smem + 44032);

    for (int c = t; c < 320; c += 256) {
        gload_lds16(w1bh_g + (size_t)v * 2560 + c * 8, (char*)w1bhS + c * 16);
        gload_lds16(w1bl_g + (size_t)v * 2560 + c * 8, (char*)w1blS + c * 16);
    }
    for (int c = t; c < 576; c += 256) {
        gload_lds16(w2bh_g + (size_t)v * 4608 + c * 8, (char*)w2bhS + c * 16);
        gload_lds16(w2bl_g + (size_t)v * 4608 + c * 8, (char*)w2blS + c * 16);
    }
#pragma unroll
    for (int i = 0; i < 2; i++) {
        int idx = t + i * 256;
        int row = idx >> 2, seg = idx & 3;
        float4 x4 = *(const float4*)(inputs + (size_t)(b0 + row) * (NVARS * LAG) + v * LAG + seg * 4);
        const float* xp = (const float*)&x4;
        short4v hv, lv;
#pragma unroll
        for (int j = 0; j < 4; j++) {
            short hi = f2bf_s(xp[j]);
            hv[j] = hi;
            lv[j] = f2bf_s(xp[j] - bf_s2f(hi));
        }
        *(short4v*)&xsS[row * 40 + seg * 4] = hv;
        *(short4v*)&xsS[row * 40 + 16 + seg * 4] = lv;
    }
    __syncthreads();

    short8 a1[2], b1hF[4], b1lF[4];
#pragma unroll
    for (int mt = 0; mt < 2; mt++)
        a1[mt] = *(const short8*)&xsS[(wv * 32 + mt * 16 + l15) * 40 + g * 8];
#pragma unroll
    for (int nt = 0; nt < 4; nt++) {
        b1hF[nt] = *(const short8*)&w1bhS[(nt * 16 + l15) * 40 + g * 8];
        b1lF[nt] = *(const short8*)&w1blS[(nt * 16 + l15) * 40 + g * 8];
    }
    f32x4 acc1[2][4];
#pragma unroll
    for (int mt = 0; mt < 2; mt++)
#pragma unroll
        for (int nt = 0; nt < 4; nt++) {
            acc1[mt][nt] = (f32x4){0.f, 0.f, 0.f, 0.f};
            acc1[mt][nt] = __builtin_amdgcn_mfma_f32_16x16x32_bf16(a1[mt], b1hF[nt], acc1[mt][nt], 0, 0, 0);
            acc1[mt][nt] = __builtin_amdgcn_mfma_f32_16x16x32_bf16(a1[mt], b1lF[nt], acc1[mt][nt], 0, 0, 0);
        }
    __syncthreads();

#pragma unroll
    for (int mt = 0; mt < 2; mt++)
#pragma unroll
        for (int nt = 0; nt < 4; nt++) {
            int col = nt * 16 + l15;
            float bias = b1g[v * H1 + col];
#pragma unroll
            for (int r = 0; r < 4; r++) {
                float h = fmaxf(acc1[mt][nt][r] + bias, 0.f);
                short hi = f2bf_s(h);
                short lo = f2bf_s(h - bf_s2f(hi));
                int row = wv * 32 + mt * 16 + g * 4 + r;
                Hs[row * 136 + col] = hi;
                Hs[row * 136 + 64 + col] = lo;
            }
        }
    __syncthreads();

    short8 a2[2][4], b2hF[4][2], b2lF[4][2];
#pragma unroll
    for (int mt = 0; mt < 2; mt++)
#pragma unroll
        for (int c = 0; c < 4; c++)
            a2[mt][c] = *(const short8*)&Hs[(wv * 32 + mt * 16 + l15) * 136 + c * 32 + g * 8];
#pragma unroll
    for (int nt = 0; nt < 4; nt++)
#pragma unroll
        for (int kc = 0; kc < 2; kc++) {
            b2hF[nt][kc] = *(const short8*)&w2bhS[(nt * 16 + l15) * 72 + kc * 32 + g * 8];
            b2lF[nt][kc] = *(const short8*)&w2blS[(nt * 16 + l15) * 72 + kc * 32 + g * 8];
        }
    f32x4 acc2[2][4];
#pragma unroll
    for (int mt = 0; mt < 2; mt++)
#pragma unroll
        for (int nt = 0; nt < 4; nt++) {
            f32x4 a = (f32x4){0.f, 0.f, 0.f, 0.f};
            a = __builtin_amdgcn_mfma_f32_16x16x32_bf16(a2[mt][0], b2hF[nt][0], a, 0, 0, 0);
            a = __builtin_amdgcn_mfma_f32_16x16x32_bf16(a2[mt][1], b2hF[nt][1], a, 0, 0, 0);
            a = __builtin_amdgcn_mfma_f32_16x16x32_bf16(a2[mt][2], b2hF[nt][0], a, 0, 0, 0);
            a = __builtin_amdgcn_mfma_f32_16x16x32_bf16(a2[mt][3], b2hF[nt][1], a, 0, 0, 0);
            a = __builtin_amdgcn_mfma_f32_16x16x32_bf16(a2[mt][0], b2lF[nt][0], a, 0, 0, 0);
            a = __builtin_amdgcn_mfma_f32_16x16x32_bf16(a2[mt][1], b2lF[nt][1], a, 0, 0, 0);
            acc2[mt][nt] = a;
        }

    const float impv = impg[v];
#pragma unroll
    for (int mt = 0; mt < 2; mt++)
#pragma unroll
        for (int nt = 0; nt < 4; nt++) {
            int col = nt * 16 + l15;
            float bias = b2g[v * H1 + col];
#pragma unroll
            for (int r = 0; r < 4; r++) {
                float o = fmaxf(acc2[mt][nt][r] + bias, 0.f) * impv;
                int row = b0 + wv * 32 + mt * 16 + g * 4 + r;
                agg[(size_t)row * KDIM + v * H1 + col] = __float2bfloat16(o);
            }
        }
}

// ---------------------------------------------------------------------------
// Kernel C: relu(agg @ W3 + b3) . W4 -> atomicAdd into out.
// 256x256 tile, BK=32, 8 waves (2Mx4N), 512 thr, deep pipeline:
//   - st_16x32 XOR swizzle (T2): LDS [256][32] bf16, rowstride 64B,
//     byte ^= ((byte>>9)&1)<<5 (== col-bit4 ^= row-bit3). Reads swizzled;
//     global_load_lds dest stays LINEAR, source address pre-swizzled.
//   - register frag double-buffer: tile t+1's frags ds_read during tile t,
//     so LDS buf[t&1] is free for staging tile t+2 (counted vmcnt(2), T3/T4).
//   - s_setprio(1) around each 16-MFMA cluster (T5).
// ---------------------------------------------------------------------------
#define NT 128   // K-tiles of 32

__global__ __launch_bounds__(512, 2) void gemm3_kernel(
    const __hip_bfloat16* __restrict__ agg,   // [16384][4096]
    const __hip_bfloat16* __restrict__ w3t,   // [1024][4096]
    const float* __restrict__ b3, const float* __restrict__ W4,
    float* __restrict__ out) {
    const int bid = blockIdx.x;               // 64 x 4 = 256 blocks
    const int brow = (bid >> 2) * 256;
    const int bcol = (bid & 3) * 256;
    const int t = threadIdx.x;
    const int lane = t & 63;
    const int wid = t >> 6;                   // 8 waves
    const int wm = wid >> 2, wn = wid & 3;    // 2 x 4, wave tile 128x64
    const int l15 = lane & 15, g = lane >> 4;

    // LDS: A bufs @0,16384 ; B bufs @32768,49152  (16 KB each)
    __shared__ __align__(16) char smem[65536];

    // --- staging: chunk c -> dest byte c*16 (linear); source col pre-swizzled
    const int c0 = t, c1 = t + 512;
    const int r0 = c0 >> 2, r1 = c1 >> 2;
    const int col0 = ((c0 & 3) * 8) ^ ((r0 & 8) ? 16 : 0);
    const int col1 = ((c1 & 3) * 8) ^ ((r1 & 8) ? 16 : 0);
    const __hip_bfloat16* aS0 = agg + (size_t)(brow + r0) * KDIM + col0;
    const __hip_bfloat16* aS1 = agg + (size_t)(brow + r1) * KDIM + col1;
    const __hip_bfloat16* bS0 = w3t + (size_t)(bcol + r0) * KDIM + col0;
    const __hip_bfloat16* bS1 = w3t + (size_t)(bcol + r1) * KDIM + col1;

#define STAGE_A(p, kt) do { \
        gload_lds16(aS0 + (kt) * 32, smem + (p) * 16384 + c0 * 16); \
        gload_lds16(aS1 + (kt) * 32, smem + (p) * 16384 + c1 * 16); } while (0)
#define STAGE_B(p, kt) do { \
        gload_lds16(bS0 + (kt) * 32, smem + 32768 + (p) * 16384 + c0 * 16); \
        gload_lds16(bS1 + (kt) * 32, smem + 32768 + (p) * 16384 + c1 * 16); } while (0)

    // --- swizzled fragment reads (row&8 == l15&8 for all m/n) ---
    const int coff = (g * 16) ^ ((l15 & 8) ? 32 : 0);
    const int aBase = (wm * 128 + l15) * 64 + coff;
    const int bBase = 32768 + (wn * 64 + l15) * 64 + coff;

#define LDA(dst, p, m) (dst) = *(const short8*)(smem + (p) * 16384 + aBase + (m) * 1024)
#define LDB(dst, p, n) (dst) = *(const short8*)(smem + (p) * 16384 + bBase + (n) * 1024)

    short8 fa[2][8], fb[2][4];
    f32x4 acc[8][4];
#pragma unroll
    for (int m = 0; m < 8; m++)
#pragma unroll
        for (int n = 0; n < 4; n++) acc[m][n] = (f32x4){0.f, 0.f, 0.f, 0.f};

    // --- prologue: stage tiles 0,1; ensure tile0 + tile1.A landed ---
    STAGE_A(0, 0); STAGE_B(0, 0);
    STAGE_A(1, 1); STAGE_B(1, 1);
    asm volatile("s_waitcnt vmcnt(2)" ::: "memory");   // tile0 A+B, tile1.A landed
    __builtin_amdgcn_s_barrier();
#pragma unroll
    for (int m = 0; m < 8; m++) LDA(fa[0][m], 0, m);
#pragma unroll
    for (int n = 0; n < 4; n++) LDB(fb[0][n], 0, n);
    asm volatile("s_waitcnt lgkmcnt(0)" ::: "memory"); // buf0 reads done ->
    __builtin_amdgcn_s_barrier();                      // safe to overwrite in loop

    // Phase(tt, CUR, NXT, MB): read half of tile tt+1's frags; stage half of
    // tile tt+2; vmcnt(2); barrier; lgkmcnt(0); 16 MFMA on CUR regs.
#define PHASE(tt, CUR, NXT, MB) \
    { \
        const int tn_ = (tt) + 1; \
        if (tn_ < NT) { \
            const int p_ = tn_ & 1; \
            if ((MB) == 0) { \
                LDA(fa[NXT][0], p_, 0); LDA(fa[NXT][1], p_, 1); \
                LDA(fa[NXT][2], p_, 2); LDA(fa[NXT][3], p_, 3); \
                LDA(fa[NXT][4], p_, 4); LDA(fa[NXT][5], p_, 5); \
            } else { \
                LDA(fa[NXT][6], p_, 6); LDA(fa[NXT][7], p_, 7); \
                LDB(fb[NXT][0], p_, 0); LDB(fb[NXT][1], p_, 1); \
                LDB(fb[NXT][2], p_, 2); LDB(fb[NXT][3], p_, 3); \
            } \
        } \
        if ((tt) + 2 < NT) { \
            if ((MB) == 0) STAGE_A((tt) & 1, (tt) + 2); \
            else           STAGE_B((tt) & 1, (tt) + 2); \
            asm volatile("s_waitcnt vmcnt(2)" ::: "memory"); \
        } else { \
            asm volatile("s_waitcnt vmcnt(0)" ::: "memory"); \
        } \
        __builtin_amdgcn_s_barrier(); \
        asm volatile("s_waitcnt lgkmcnt(0)" ::: "memory"); \
        __builtin_amdgcn_sched_barrier(0); \
        __builtin_amdgcn_s_setprio(1); \
        _Pragma("unroll") \
        for (int mm = 0; mm < 4; mm++) \
            _Pragma("unroll") \
            for (int nn = 0; nn < 4; nn++) \
                acc[(MB) + mm][nn] = __builtin_amdgcn_mfma_f32_16x16x32_bf16( \
                    fa[CUR][(MB) + mm], fb[CUR][nn], acc[(MB) + mm][nn], 0, 0, 0); \
        __builtin_amdgcn_s_setprio(0); \
        __builtin_amdgcn_s_barrier(); \
    }

    for (int t2 = 0; t2 < NT / 2; t2++) {
        const int tt = t2 * 2;
        PHASE(tt,     0, 1, 0)
        PHASE(tt,     0, 1, 4)
        PHASE(tt + 1, 1, 0, 0)
        PHASE(tt + 1, 1, 0, 4)
    }

    // --- epilogue: bias+relu, dot W4, 16-lane reduce, atomicAdd per row ---
    float bias[4], w4v[4];
#pragma unroll
    for (int n = 0; n < 4; n++) {
        int col = bcol + wn * 64 + n * 16 + l15;
        bias[n] = b3[col];
        w4v[n] = W4[col];
    }
#pragma unroll
    for (int m = 0; m < 8; m++) {
        float pr0 = 0.f, pr1 = 0.f, pr2 = 0.f, pr3 = 0.f;
#pragma unroll
        for (int n = 0; n < 4; n++) {
            pr0 += fmaxf(acc[m][n][0] + bias[n], 0.f) * w4v[n];
            pr1 += fmaxf(acc[m][n][1] + bias[n], 0.f) * w4v[n];
            pr2 += fmaxf(acc[m][n][2] + bias[n], 0.f) * w4v[n];
            pr3 += fmaxf(acc[m][n][3] + bias[n], 0.f) * w4v[n];
        }
#pragma unroll
        for (int mask = 1; mask < 16; mask <<= 1) {
            pr0 += __shfl_xor(pr0, mask, 64);
            pr1 += __shfl_xor(pr1, mask, 64);
            pr2 += __shfl_xor(pr2, mask, 64);
            pr3 += __shfl_xor(pr3, mask, 64);
        }
        if (l15 == 0) {
            int row = brow + wm * 128 + m * 16 + g * 4;
            atomicAdd(&out[row + 0], pr0);
            atomicAdd(&out[row + 1], pr1);
            atomicAdd(&out[row + 2], pr2);
            atomicAdd(&out[row + 3], pr3);
        }
    }
}

// ---------------------------------------------------------------------------
extern "C" void kernel_launch(void* const* d_in, const int* in_sizes, int n_in,
                              void* d_out, int out_size, void* d_ws, size_t ws_size,
                              hipStream_t stream) {
    const float* inputs = (const float*)d_in[0];
    const float* W1 = (const float*)d_in[1];
    const float* b1 = (const float*)d_in[2];
    const float* W2 = (const float*)d_in[3];
    const float* b2 = (const float*)d_in[4];
    const float* imp = (const float*)d_in[5];
    const float* W3 = (const float*)d_in[6];
    const float* b3 = (const float*)d_in[7];
    const float* W4 = (const float*)d_in[8];
    const float* b4 = (const float*)d_in[9];
    float* out = (float*)d_out;

    char* ws = (char*)d_ws;
    const size_t agg_bytes  = (size_t)B_ROWS * KDIM * 2;
    const size_t w3t_bytes  = (size_t)H2 * KDIM * 2;
    const size_t w1b_bytes  = (size_t)NVARS * 64 * 40 * 2;
    const size_t w2b_bytes  = (size_t)NVARS * 64 * 72 * 2;

    __hip_bfloat16* agg = (__hip_bfloat16*)ws;
    __hip_bfloat16* w3t = (__hip_bfloat16*)(ws + agg_bytes);
    short* w1bh = (short*)(ws + agg_bytes + w3t_bytes);
    short* w1bl = (short*)(ws + agg_bytes + w3t_bytes + w1b_bytes);
    short* w2bh = (short*)(ws + agg_bytes + w3t_bytes + 2 * w1b_bytes);
    short* w2bl = (short*)(ws + agg_bytes + w3t_bytes + 2 * w1b_bytes + w2b_bytes);

    hipLaunchKernelGGL(convert_w3t_kernel, dim3(1024), dim3(256), 0, stream, W3, w3t);
    hipLaunchKernelGGL(prep_w12_kernel, dim3(NVARS), dim3(256), 0, stream,
                       W1, W2, w1bh, w1bl, w2bh, w2bl);
    hipLaunchKernelGGL(out_init_kernel, dim3(B_ROWS / 256), dim3(256), 0, stream, b4, out);
    hipLaunchKernelGGL(subnets_mfma_kernel, dim3(NVARS * (B_ROWS / 128)), dim3(256), 0, stream,
                       inputs, b1, b2, imp, w1bh, w1bl, w2bh, w2bl, agg);
    hipLaunchKernelGGL(gemm3_kernel, dim3((B_ROWS / 256) * (H2 / 256)), dim3(512), 0, stream,
                       agg, w3t, b3, W4, out);
}

// Round 4
// 184.825 us; speedup vs baseline: 2.7939x; 1.2019x over previous
//
#include <hip/hip_runtime.h>
#include <hip/hip_bf16.h>
#include <stdint.h>

#define B_ROWS 16384
#define NVARS 64
#define LAG 16
#define H1 64
#define H2 1024
#define KDIM (NVARS * H1)   // 4096

typedef __attribute__((ext_vector_type(8))) short short8;
typedef __attribute__((ext_vector_type(4))) short short4v;
typedef __attribute__((ext_vector_type(4))) float f32x4;

typedef __attribute__((address_space(3))) uint8_t lds_u8;
typedef const __attribute__((address_space(1))) uint8_t glob_u8;

__device__ __forceinline__ void gload_lds16(const void* g, void* l) {
    __builtin_amdgcn_global_load_lds((glob_u8*)g, (lds_u8*)l, 16, 0, 0);
}

__device__ __forceinline__ short f2bf_s(float x) {
    __hip_bfloat16 h = __float2bfloat16(x);
    return *(short*)&h;
}
__device__ __forceinline__ float bf_s2f(short s) {
    __hip_bfloat16 h = *(__hip_bfloat16*)&s;
    return __bfloat162float(h);
}

// ---------------------------------------------------------------------------
// Kernel A: W3 [4096][1024] f32 -> W3T [1024][4096] bf16 (tiled transpose)
// ---------------------------------------------------------------------------
__global__ __launch_bounds__(256) void convert_w3t_kernel(
    const float* __restrict__ w3, __hip_bfloat16* __restrict__ w3t) {
    __shared__ float tile[64][65];
    const int bx = blockIdx.x;
    const int k0 = (bx >> 4) * 64;
    const int n0 = (bx & 15) * 64;
    const int t = threadIdx.x;
    const int c = t & 63, r0 = t >> 6;
#pragma unroll
    for (int i = 0; i < 16; i++) {
        int r = r0 + i * 4;
        tile[r][c] = w3[(size_t)(k0 + r) * H2 + n0 + c];
    }
    __syncthreads();
#pragma unroll
    for (int i = 0; i < 16; i++) {
        int nr = r0 + i * 4;
        w3t[(size_t)(n0 + nr) * KDIM + k0 + c] = __float2bfloat16(tile[c][nr]);
    }
}

// ---------------------------------------------------------------------------
// Kernel A2: build hi/lo B-operand (transposed, padded) tiles for W1, W2.
// ---------------------------------------------------------------------------
__global__ __launch_bounds__(256) void prep_w12_kernel(
    const float* __restrict__ W1, const float* __restrict__ W2,
    short* __restrict__ w1bh, short* __restrict__ w1bl,
    short* __restrict__ w2bh, short* __restrict__ w2bl) {
    const int v = blockIdx.x, t = threadIdx.x;
    for (int idx = t; idx < 64 * 32; idx += 256) {
        int col = idx >> 5, k = idx & 31;
        float wv = W1[((size_t)v * LAG + (k & 15)) * H1 + col];
        short hi = f2bf_s(wv);
        w1bh[((size_t)v * 64 + col) * 40 + k] = hi;
        w1bl[((size_t)v * 64 + col) * 40 + k] = (k < 16) ? f2bf_s(wv - bf_s2f(hi)) : (short)0;
    }
    for (int idx = t; idx < 64 * 64; idx += 256) {
        int col = idx >> 6, k = idx & 63;
        float wv = W2[((size_t)v * H1 + k) * H1 + col];
        short hi = f2bf_s(wv);
        w2bh[((size_t)v * 64 + col) * 72 + k] = hi;
        w2bl[((size_t)v * 64 + col) * 72 + k] = f2bf_s(wv - bf_s2f(hi));
    }
}

// ---------------------------------------------------------------------------
// Kernel A3: out[i] = b4[0]  (gemm3 atomically accumulates the W4 dot on top)
// ---------------------------------------------------------------------------
__global__ __launch_bounds__(256) void out_init_kernel(
    const float* __restrict__ b4, float* __restrict__ out) {
    out[blockIdx.x * 256 + threadIdx.x] = b4[0];
}

// ---------------------------------------------------------------------------
// Kernel B: per-variable 2-layer subnet via split-bf16 MFMA (validated r2).
// ---------------------------------------------------------------------------
__global__ __launch_bounds__(256) void subnets_mfma_kernel(
    const float* __restrict__ inputs, const float* __restrict__ b1g,
    const float* __restrict__ b2g, const float* __restrict__ impg,
    const short* __restrict__ w1bh_g, const short* __restrict__ w1bl_g,
    const short* __restrict__ w2bh_g, const short* __restrict__ w2bl_g,
    __hip_bfloat16* __restrict__ agg) {
    const int v = blockIdx.x >> 7;
    const int b0 = (blockIdx.x & 127) * 128;
    const int t = threadIdx.x;
    const int lane = t & 63, wv = t >> 6;
    const int l15 = lane & 15, g = lane >> 4;

    __shared__ __align__(16) char smem[53248];
    short* xsS   = (short*)smem;
    short* w1bhS = (short*)(smem + 10240);
    short* w1blS = (short*)(smem + 15360);
    short* Hs    = (short*)smem;
    short* w2bhS = (short*)(smem + 34816);
    short* w2blS = (short*)(smem + 44032);

    for (int c = t; c < 320; c += 256) {
        gload_lds16(w1bh_g + (size_t)v * 2560 + c * 8, (char*)w1bhS + c * 16);
        gload_lds16(w1bl_g + (size_t)v * 2560 + c * 8, (char*)w1blS + c * 16);
    }
    for (int c = t; c < 576; c += 256) {
        gload_lds16(w2bh_g + (size_t)v * 4608 + c * 8, (char*)w2bhS + c * 16);
        gload_lds16(w2bl_g + (size_t)v * 4608 + c * 8, (char*)w2blS + c * 16);
    }
#pragma unroll
    for (int i = 0; i < 2; i++) {
        int idx = t + i * 256;
        int row = idx >> 2, seg = idx & 3;
        float4 x4 = *(const float4*)(inputs + (size_t)(b0 + row) * (NVARS * LAG) + v * LAG + seg * 4);
        const float* xp = (const float*)&x4;
        short4v hv, lv;
#pragma unroll
        for (int j = 0; j < 4; j++) {
            short hi = f2bf_s(xp[j]);
            hv[j] = hi;
            lv[j] = f2bf_s(xp[j] - bf_s2f(hi));
        }
        *(short4v*)&xsS[row * 40 + seg * 4] = hv;
        *(short4v*)&xsS[row * 40 + 16 + seg * 4] = lv;
    }
    __syncthreads();

    short8 a1[2], b1hF[4], b1lF[4];
#pragma unroll
    for (int mt = 0; mt < 2; mt++)
        a1[mt] = *(const short8*)&xsS[(wv * 32 + mt * 16 + l15) * 40 + g * 8];
#pragma unroll
    for (int nt = 0; nt < 4; nt++) {
        b1hF[nt] = *(const short8*)&w1bhS[(nt * 16 + l15) * 40 + g * 8];
        b1lF[nt] = *(const short8*)&w1blS[(nt * 16 + l15) * 40 + g * 8];
    }
    f32x4 acc1[2][4];
#pragma unroll
    for (int mt = 0; mt < 2; mt++)
#pragma unroll
        for (int nt = 0; nt < 4; nt++) {
            acc1[mt][nt] = (f32x4){0.f, 0.f, 0.f, 0.f};
            acc1[mt][nt] = __builtin_amdgcn_mfma_f32_16x16x32_bf16(a1[mt], b1hF[nt], acc1[mt][nt], 0, 0, 0);
            acc1[mt][nt] = __builtin_amdgcn_mfma_f32_16x16x32_bf16(a1[mt], b1lF[nt], acc1[mt][nt], 0, 0, 0);
        }
    __syncthreads();

#pragma unroll
    for (int mt = 0; mt < 2; mt++)
#pragma unroll
        for (int nt = 0; nt < 4; nt++) {
            int col = nt * 16 + l15;
            float bias = b1g[v * H1 + col];
#pragma unroll
            for (int r = 0; r < 4; r++) {
                float h = fmaxf(acc1[mt][nt][r] + bias, 0.f);
                short hi = f2bf_s(h);
                short lo = f2bf_s(h - bf_s2f(hi));
                int row = wv * 32 + mt * 16 + g * 4 + r;
                Hs[row * 136 + col] = hi;
                Hs[row * 136 + 64 + col] = lo;
            }
        }
    __syncthreads();

    short8 a2[2][4], b2hF[4][2], b2lF[4][2];
#pragma unroll
    for (int mt = 0; mt < 2; mt++)
#pragma unroll
        for (int c = 0; c < 4; c++)
            a2[mt][c] = *(const short8*)&Hs[(wv * 32 + mt * 16 + l15) * 136 + c * 32 + g * 8];
#pragma unroll
    for (int nt = 0; nt < 4; nt++)
#pragma unroll
        for (int kc = 0; kc < 2; kc++) {
            b2hF[nt][kc] = *(const short8*)&w2bhS[(nt * 16 + l15) * 72 + kc * 32 + g * 8];
            b2lF[nt][kc] = *(const short8*)&w2blS[(nt * 16 + l15) * 72 + kc * 32 + g * 8];
        }
    f32x4 acc2[2][4];
#pragma unroll
    for (int mt = 0; mt < 2; mt++)
#pragma unroll
        for (int nt = 0; nt < 4; nt++) {
            f32x4 a = (f32x4){0.f, 0.f, 0.f, 0.f};
            a = __builtin_amdgcn_mfma_f32_16x16x32_bf16(a2[mt][0], b2hF[nt][0], a, 0, 0, 0);
            a = __builtin_amdgcn_mfma_f32_16x16x32_bf16(a2[mt][1], b2hF[nt][1], a, 0, 0, 0);
            a = __builtin_amdgcn_mfma_f32_16x16x32_bf16(a2[mt][2], b2hF[nt][0], a, 0, 0, 0);
            a = __builtin_amdgcn_mfma_f32_16x16x32_bf16(a2[mt][3], b2hF[nt][1], a, 0, 0, 0);
            a = __builtin_amdgcn_mfma_f32_16x16x32_bf16(a2[mt][0], b2lF[nt][0], a, 0, 0, 0);
            a = __builtin_amdgcn_mfma_f32_16x16x32_bf16(a2[mt][1], b2lF[nt][1], a, 0, 0, 0);
            acc2[mt][nt] = a;
        }

    const float impv = impg[v];
#pragma unroll
    for (int mt = 0; mt < 2; mt++)
#pragma unroll
        for (int nt = 0; nt < 4; nt++) {
            int col = nt * 16 + l15;
            float bias = b2g[v * H1 + col];
#pragma unroll
            for (int r = 0; r < 4; r++) {
                float o = fmaxf(acc2[mt][nt][r] + bias, 0.f) * impv;
                int row = b0 + wv * 32 + mt * 16 + g * 4 + r;
                agg[(size_t)row * KDIM + v * H1 + col] = __float2bfloat16(o);
            }
        }
}

// ---------------------------------------------------------------------------
// Kernel C: relu(agg @ W3 + b3) . W4 -> atomicAdd into out.
// 256x256 tile, BK=32, 8 waves (2Mx4N), 512 thr, deep pipeline (r3-validated)
// + bijective chunked XCD swizzle (T1): each XCD owns 8 contiguous row-panels
//   so the 4 col-tiles sharing an A panel hit the SAME per-XCD L2.
// ---------------------------------------------------------------------------
#define NT 128   // K-tiles of 32

__global__ __launch_bounds__(512, 2) void gemm3_kernel(
    const __hip_bfloat16* __restrict__ agg,   // [16384][4096]
    const __hip_bfloat16* __restrict__ w3t,   // [1024][4096]
    const float* __restrict__ b3, const float* __restrict__ W4,
    float* __restrict__ out) {
    // XCD swizzle: 256 blocks, 8 XCDs (hw assigns XCD = blockIdx % 8).
    // swz = (bid&7)*32 + (bid>>3): XCD x gets bids [32x, 32x+32) = 8 full
    // row-panels (4 col-tiles each) -> A panel fetched into exactly one L2.
    const int bid = ((blockIdx.x & 7) << 5) + (blockIdx.x >> 3);
    const int brow = (bid >> 2) * 256;
    const int bcol = (bid & 3) * 256;
    const int t = threadIdx.x;
    const int lane = t & 63;
    const int wid = t >> 6;                   // 8 waves
    const int wm = wid >> 2, wn = wid & 3;    // 2 x 4, wave tile 128x64
    const int l15 = lane & 15, g = lane >> 4;

    // LDS: A bufs @0,16384 ; B bufs @32768,49152  (16 KB each)
    __shared__ __align__(16) char smem[65536];

    // --- staging: chunk c -> dest byte c*16 (linear); source col pre-swizzled
    const int c0 = t, c1 = t + 512;
    const int r0 = c0 >> 2, r1 = c1 >> 2;
    const int col0 = ((c0 & 3) * 8) ^ ((r0 & 8) ? 16 : 0);
    const int col1 = ((c1 & 3) * 8) ^ ((r1 & 8) ? 16 : 0);
    const __hip_bfloat16* aS0 = agg + (size_t)(brow + r0) * KDIM + col0;
    const __hip_bfloat16* aS1 = agg + (size_t)(brow + r1) * KDIM + col1;
    const __hip_bfloat16* bS0 = w3t + (size_t)(bcol + r0) * KDIM + col0;
    const __hip_bfloat16* bS1 = w3t + (size_t)(bcol + r1) * KDIM + col1;

#define STAGE_A(p, kt) do { \
        gload_lds16(aS0 + (kt) * 32, smem + (p) * 16384 + c0 * 16); \
        gload_lds16(aS1 + (kt) * 32, smem + (p) * 16384 + c1 * 16); } while (0)
#define STAGE_B(p, kt) do { \
        gload_lds16(bS0 + (kt) * 32, smem + 32768 + (p) * 16384 + c0 * 16); \
        gload_lds16(bS1 + (kt) * 32, smem + 32768 + (p) * 16384 + c1 * 16); } while (0)

    // --- swizzled fragment reads (row&8 == l15&8 for all m/n) ---
    const int coff = (g * 16) ^ ((l15 & 8) ? 32 : 0);
    const int aBase = (wm * 128 + l15) * 64 + coff;
    const int bBase = 32768 + (wn * 64 + l15) * 64 + coff;

#define LDA(dst, p, m) (dst) = *(const short8*)(smem + (p) * 16384 + aBase + (m) * 1024)
#define LDB(dst, p, n) (dst) = *(const short8*)(smem + (p) * 16384 + bBase + (n) * 1024)

    short8 fa[2][8], fb[2][4];
    f32x4 acc[8][4];
#pragma unroll
    for (int m = 0; m < 8; m++)
#pragma unroll
        for (int n = 0; n < 4; n++) acc[m][n] = (f32x4){0.f, 0.f, 0.f, 0.f};

    // --- prologue: stage tiles 0,1; ensure tile0 + tile1.A landed ---
    STAGE_A(0, 0); STAGE_B(0, 0);
    STAGE_A(1, 1); STAGE_B(1, 1);
    asm volatile("s_waitcnt vmcnt(2)" ::: "memory");   // tile0 A+B, tile1.A landed
    __builtin_amdgcn_s_barrier();
#pragma unroll
    for (int m = 0; m < 8; m++) LDA(fa[0][m], 0, m);
#pragma unroll
    for (int n = 0; n < 4; n++) LDB(fb[0][n], 0, n);
    asm volatile("s_waitcnt lgkmcnt(0)" ::: "memory"); // buf0 reads done ->
    __builtin_amdgcn_s_barrier();                      // safe to overwrite in loop

    // Phase(tt, CUR, NXT, MB): read half of tile tt+1's frags; stage half of
    // tile tt+2; vmcnt(2); barrier; lgkmcnt(0); 16 MFMA on CUR regs.
#define PHASE(tt, CUR, NXT, MB) \
    { \
        const int tn_ = (tt) + 1; \
        if (tn_ < NT) { \
            const int p_ = tn_ & 1; \
            if ((MB) == 0) { \
                LDA(fa[NXT][0], p_, 0); LDA(fa[NXT][1], p_, 1); \
                LDA(fa[NXT][2], p_, 2); LDA(fa[NXT][3], p_, 3); \
                LDA(fa[NXT][4], p_, 4); LDA(fa[NXT][5], p_, 5); \
            } else { \
                LDA(fa[NXT][6], p_, 6); LDA(fa[NXT][7], p_, 7); \
                LDB(fb[NXT][0], p_, 0); LDB(fb[NXT][1], p_, 1); \
                LDB(fb[NXT][2], p_, 2); LDB(fb[NXT][3], p_, 3); \
            } \
        } \
        if ((tt) + 2 < NT) { \
            if ((MB) == 0) STAGE_A((tt) & 1, (tt) + 2); \
            else           STAGE_B((tt) & 1, (tt) + 2); \
            asm volatile("s_waitcnt vmcnt(2)" ::: "memory"); \
        } else { \
            asm volatile("s_waitcnt vmcnt(0)" ::: "memory"); \
        } \
        __builtin_amdgcn_s_barrier(); \
        asm volatile("s_waitcnt lgkmcnt(0)" ::: "memory"); \
        __builtin_amdgcn_sched_barrier(0); \
        __builtin_amdgcn_s_setprio(1); \
        _Pragma("unroll") \
        for (int mm = 0; mm < 4; mm++) \
            _Pragma("unroll") \
            for (int nn = 0; nn < 4; nn++) \
                acc[(MB) + mm][nn] = __builtin_amdgcn_mfma_f32_16x16x32_bf16( \
                    fa[CUR][(MB) + mm], fb[CUR][nn], acc[(MB) + mm][nn], 0, 0, 0); \
        __builtin_amdgcn_s_setprio(0); \
        __builtin_amdgcn_s_barrier(); \
    }

    for (int t2 = 0; t2 < NT / 2; t2++) {
        const int tt = t2 * 2;
        PHASE(tt,     0, 1, 0)
        PHASE(tt,     0, 1, 4)
        PHASE(tt + 1, 1, 0, 0)
        PHASE(tt + 1, 1, 0, 4)
    }

    // --- epilogue: bias+relu, dot W4, 16-lane reduce, atomicAdd per row ---
    float bias[4], w4v[4];
#pragma unroll
    for (int n = 0; n < 4; n++) {
        int col = bcol + wn * 64 + n * 16 + l15;
        bias[n] = b3[col];
        w4v[n] = W4[col];
    }
#pragma unroll
    for (int m = 0; m < 8; m++) {
        float pr0 = 0.f, pr1 = 0.f, pr2 = 0.f, pr3 = 0.f;
#pragma unroll
        for (int n = 0; n < 4; n++) {
            pr0 += fmaxf(acc[m][n][0] + bias[n], 0.f) * w4v[n];
            pr1 += fmaxf(acc[m][n][1] + bias[n], 0.f) * w4v[n];
            pr2 += fmaxf(acc[m][n][2] + bias[n], 0.f) * w4v[n];
            pr3 += fmaxf(acc[m][n][3] + bias[n], 0.f) * w4v[n];
        }
#pragma unroll
        for (int mask = 1; mask < 16; mask <<= 1) {
            pr0 += __shfl_xor(pr0, mask, 64);
            pr1 += __shfl_xor(pr1, mask, 64);
            pr2 += __shfl_xor(pr2, mask, 64);
            pr3 += __shfl_xor(pr3, mask, 64);
        }
        if (l15 == 0) {
            int row = brow + wm * 128 + m * 16 + g * 4;
            atomicAdd(&out[row + 0], pr0);
            atomicAdd(&out[row + 1], pr1);
            atomicAdd(&out[row + 2], pr2);
            atomicAdd(&out[row + 3], pr3);
        }
    }
}

// ---------------------------------------------------------------------------
extern "C" void kernel_launch(void* const* d_in, const int* in_sizes, int n_in,
                              void* d_out, int out_size, void* d_ws, size_t ws_size,
                              hipStream_t stream) {
    const float* inputs = (const float*)d_in[0];
    const float* W1 = (const float*)d_in[1];
    const float* b1 = (const float*)d_in[2];
    const float* W2 = (const float*)d_in[3];
    const float* b2 = (const float*)d_in[4];
    const float* imp = (const float*)d_in[5];
    const float* W3 = (const float*)d_in[6];
    const float* b3 = (const float*)d_in[7];
    const float* W4 = (const float*)d_in[8];
    const float* b4 = (const float*)d_in[9];
    float* out = (float*)d_out;

    char* ws = (char*)d_ws;
    const size_t agg_bytes  = (size_t)B_ROWS * KDIM * 2;
    const size_t w3t_bytes  = (size_t)H2 * KDIM * 2;
    const size_t w1b_bytes  = (size_t)NVARS * 64 * 40 * 2;
    const size_t w2b_bytes  = (size_t)NVARS * 64 * 72 * 2;

    __hip_bfloat16* agg = (__hip_bfloat16*)ws;
    __hip_bfloat16* w3t = (__hip_bfloat16*)(ws + agg_bytes);
    short* w1bh = (short*)(ws + agg_bytes + w3t_bytes);
    short* w1bl = (short*)(ws + agg_bytes + w3t_bytes + w1b_bytes);
    short* w2bh = (short*)(ws + agg_bytes + w3t_bytes + 2 * w1b_bytes);
    short* w2bl = (short*)(ws + agg_bytes + w3t_bytes + 2 * w1b_bytes + w2b_bytes);

    hipLaunchKernelGGL(convert_w3t_kernel, dim3(1024), dim3(256), 0, stream, W3, w3t);
    hipLaunchKernelGGL(prep_w12_kernel, dim3(NVARS), dim3(256), 0, stream,
                       W1, W2, w1bh, w1bl, w2bh, w2bl);
    hipLaunchKernelGGL(out_init_kernel, dim3(B_ROWS / 256), dim3(256), 0, stream, b4, out);
    hipLaunchKernelGGL(subnets_mfma_kernel, dim3(NVARS * (B_ROWS / 128)), dim3(256), 0, stream,
                       inputs, b1, b2, imp, w1bh, w1bl, w2bh, w2bl, agg);
    hipLaunchKernelGGL(gemm3_kernel, dim3((B_ROWS / 256) * (H2 / 256)), dim3(512), 0, stream,
                       agg, w3t, b3, W4, out);
}

// Round 5
// 181.404 us; speedup vs baseline: 2.8465x; 1.0189x over previous
//
#include <hip/hip_runtime.h>
#include <hip/hip_bf16.h>
#include <stdint.h>

#define B_ROWS 16384
#define NVARS 64
#define LAG 16
#define H1 64
#define H2 1024
#define KDIM (NVARS * H1)   // 4096

typedef __attribute__((ext_vector_type(8))) short short8;
typedef __attribute__((ext_vector_type(4))) short short4v;
typedef __attribute__((ext_vector_type(4))) float f32x4;

typedef __attribute__((address_space(3))) uint8_t lds_u8;
typedef const __attribute__((address_space(1))) uint8_t glob_u8;

__device__ __forceinline__ void gload_lds16(const void* g, void* l) {
    __builtin_amdgcn_global_load_lds((glob_u8*)g, (lds_u8*)l, 16, 0, 0);
}

__device__ __forceinline__ short f2bf_s(float x) {
    __hip_bfloat16 h = __float2bfloat16(x);
    return *(short*)&h;
}
__device__ __forceinline__ float bf_s2f(short s) {
    __hip_bfloat16 h = *(__hip_bfloat16*)&s;
    return __bfloat162float(h);
}

// ---------------------------------------------------------------------------
// Kernel A: W3 [4096][1024] f32 -> W3T [1024][4096] bf16 (tiled transpose)
// ---------------------------------------------------------------------------
__global__ __launch_bounds__(256) void convert_w3t_kernel(
    const float* __restrict__ w3, __hip_bfloat16* __restrict__ w3t) {
    __shared__ float tile[64][65];
    const int bx = blockIdx.x;
    const int k0 = (bx >> 4) * 64;
    const int n0 = (bx & 15) * 64;
    const int t = threadIdx.x;
    const int c = t & 63, r0 = t >> 6;
#pragma unroll
    for (int i = 0; i < 16; i++) {
        int r = r0 + i * 4;
        tile[r][c] = w3[(size_t)(k0 + r) * H2 + n0 + c];
    }
    __syncthreads();
#pragma unroll
    for (int i = 0; i < 16; i++) {
        int nr = r0 + i * 4;
        w3t[(size_t)(n0 + nr) * KDIM + k0 + c] = __float2bfloat16(tile[c][nr]);
    }
}

// ---------------------------------------------------------------------------
// Kernel A2: build hi/lo B-operand (transposed, padded) tiles for W1, W2.
// ---------------------------------------------------------------------------
__global__ __launch_bounds__(256) void prep_w12_kernel(
    const float* __restrict__ W1, const float* __restrict__ W2,
    short* __restrict__ w1bh, short* __restrict__ w1bl,
    short* __restrict__ w2bh, short* __restrict__ w2bl) {
    const int v = blockIdx.x, t = threadIdx.x;
    for (int idx = t; idx < 64 * 32; idx += 256) {
        int col = idx >> 5, k = idx & 31;
        float wv = W1[((size_t)v * LAG + (k & 15)) * H1 + col];
        short hi = f2bf_s(wv);
        w1bh[((size_t)v * 64 + col) * 40 + k] = hi;
        w1bl[((size_t)v * 64 + col) * 40 + k] = (k < 16) ? f2bf_s(wv - bf_s2f(hi)) : (short)0;
    }
    for (int idx = t; idx < 64 * 64; idx += 256) {
        int col = idx >> 6, k = idx & 63;
        float wv = W2[((size_t)v * H1 + k) * H1 + col];
        short hi = f2bf_s(wv);
        w2bh[((size_t)v * 64 + col) * 72 + k] = hi;
        w2bl[((size_t)v * 64 + col) * 72 + k] = f2bf_s(wv - bf_s2f(hi));
    }
}

// ---------------------------------------------------------------------------
// Kernel A3: out[i] = b4[0]  (gemm3 atomically accumulates the W4 dot on top)
// ---------------------------------------------------------------------------
__global__ __launch_bounds__(256) void out_init_kernel(
    const float* __restrict__ b4, float* __restrict__ out) {
    out[blockIdx.x * 256 + threadIdx.x] = b4[0];
}

// ---------------------------------------------------------------------------
// Kernel B: per-variable 2-layer subnet via split-bf16 MFMA (validated r2).
// ---------------------------------------------------------------------------
__global__ __launch_bounds__(256) void subnets_mfma_kernel(
    const float* __restrict__ inputs, const float* __restrict__ b1g,
    const float* __restrict__ b2g, const float* __restrict__ impg,
    const short* __restrict__ w1bh_g, const short* __restrict__ w1bl_g,
    const short* __restrict__ w2bh_g, const short* __restrict__ w2bl_g,
    __hip_bfloat16* __restrict__ agg) {
    const int v = blockIdx.x >> 7;
    const int b0 = (blockIdx.x & 127) * 128;
    const int t = threadIdx.x;
    const int lane = t & 63, wv = t >> 6;
    const int l15 = lane & 15, g = lane >> 4;

    __shared__ __align__(16) char smem[53248];
    short* xsS   = (short*)smem;
    short* w1bhS = (short*)(smem + 10240);
    short* w1blS = (short*)(smem + 15360);
    short* Hs    = (short*)smem;
    short* w2bhS = (short*)(smem + 34816);
    short* w2blS = (short*)(smem + 44032);

    for (int c = t; c < 320; c += 256) {
        gload_lds16(w1bh_g + (size_t)v * 2560 + c * 8, (char*)w1bhS + c * 16);
        gload_lds16(w1bl_g + (size_t)v * 2560 + c * 8, (char*)w1blS + c * 16);
    }
    for (int c = t; c < 576; c += 256) {
        gload_lds16(w2bh_g + (size_t)v * 4608 + c * 8, (char*)w2bhS + c * 16);
        gload_lds16(w2bl_g + (size_t)v * 4608 + c * 8, (char*)w2blS + c * 16);
    }
#pragma unroll
    for (int i = 0; i < 2; i++) {
        int idx = t + i * 256;
        int row = idx >> 2, seg = idx & 3;
        float4 x4 = *(const float4*)(inputs + (size_t)(b0 + row) * (NVARS * LAG) + v * LAG + seg * 4);
        const float* xp = (const float*)&x4;
        short4v hv, lv;
#pragma unroll
        for (int j = 0; j < 4; j++) {
            short hi = f2bf_s(xp[j]);
            hv[j] = hi;
            lv[j] = f2bf_s(xp[j] - bf_s2f(hi));
        }
        *(short4v*)&xsS[row * 40 + seg * 4] = hv;
        *(short4v*)&xsS[row * 40 + 16 + seg * 4] = lv;
    }
    __syncthreads();

    short8 a1[2], b1hF[4], b1lF[4];
#pragma unroll
    for (int mt = 0; mt < 2; mt++)
        a1[mt] = *(const short8*)&xsS[(wv * 32 + mt * 16 + l15) * 40 + g * 8];
#pragma unroll
    for (int nt = 0; nt < 4; nt++) {
        b1hF[nt] = *(const short8*)&w1bhS[(nt * 16 + l15) * 40 + g * 8];
        b1lF[nt] = *(const short8*)&w1blS[(nt * 16 + l15) * 40 + g * 8];
    }
    f32x4 acc1[2][4];
#pragma unroll
    for (int mt = 0; mt < 2; mt++)
#pragma unroll
        for (int nt = 0; nt < 4; nt++) {
            acc1[mt][nt] = (f32x4){0.f, 0.f, 0.f, 0.f};
            acc1[mt][nt] = __builtin_amdgcn_mfma_f32_16x16x32_bf16(a1[mt], b1hF[nt], acc1[mt][nt], 0, 0, 0);
            acc1[mt][nt] = __builtin_amdgcn_mfma_f32_16x16x32_bf16(a1[mt], b1lF[nt], acc1[mt][nt], 0, 0, 0);
        }
    __syncthreads();

#pragma unroll
    for (int mt = 0; mt < 2; mt++)
#pragma unroll
        for (int nt = 0; nt < 4; nt++) {
            int col = nt * 16 + l15;
            float bias = b1g[v * H1 + col];
#pragma unroll
            for (int r = 0; r < 4; r++) {
                float h = fmaxf(acc1[mt][nt][r] + bias, 0.f);
                short hi = f2bf_s(h);
                short lo = f2bf_s(h - bf_s2f(hi));
                int row = wv * 32 + mt * 16 + g * 4 + r;
                Hs[row * 136 + col] = hi;
                Hs[row * 136 + 64 + col] = lo;
            }
        }
    __syncthreads();

    short8 a2[2][4], b2hF[4][2], b2lF[4][2];
#pragma unroll
    for (int mt = 0; mt < 2; mt++)
#pragma unroll
        for (int c = 0; c < 4; c++)
            a2[mt][c] = *(const short8*)&Hs[(wv * 32 + mt * 16 + l15) * 136 + c * 32 + g * 8];
#pragma unroll
    for (int nt = 0; nt < 4; nt++)
#pragma unroll
        for (int kc = 0; kc < 2; kc++) {
            b2hF[nt][kc] = *(const short8*)&w2bhS[(nt * 16 + l15) * 72 + kc * 32 + g * 8];
            b2lF[nt][kc] = *(const short8*)&w2blS[(nt * 16 + l15) * 72 + kc * 32 + g * 8];
        }
    f32x4 acc2[2][4];
#pragma unroll
    for (int mt = 0; mt < 2; mt++)
#pragma unroll
        for (int nt = 0; nt < 4; nt++) {
            f32x4 a = (f32x4){0.f, 0.f, 0.f, 0.f};
            a = __builtin_amdgcn_mfma_f32_16x16x32_bf16(a2[mt][0], b2hF[nt][0], a, 0, 0, 0);
            a = __builtin_amdgcn_mfma_f32_16x16x32_bf16(a2[mt][1], b2hF[nt][1], a, 0, 0, 0);
            a = __builtin_amdgcn_mfma_f32_16x16x32_bf16(a2[mt][2], b2hF[nt][0], a, 0, 0, 0);
            a = __builtin_amdgcn_mfma_f32_16x16x32_bf16(a2[mt][3], b2hF[nt][1], a, 0, 0, 0);
            a = __builtin_amdgcn_mfma_f32_16x16x32_bf16(a2[mt][0], b2lF[nt][0], a, 0, 0, 0);
            a = __builtin_amdgcn_mfma_f32_16x16x32_bf16(a2[mt][1], b2lF[nt][1], a, 0, 0, 0);
            acc2[mt][nt] = a;
        }

    const float impv = impg[v];
#pragma unroll
    for (int mt = 0; mt < 2; mt++)
#pragma unroll
        for (int nt = 0; nt < 4; nt++) {
            int col = nt * 16 + l15;
            float bias = b2g[v * H1 + col];
#pragma unroll
            for (int r = 0; r < 4; r++) {
                float o = fmaxf(acc2[mt][nt][r] + bias, 0.f) * impv;
                int row = b0 + wv * 32 + mt * 16 + g * 4 + r;
                agg[(size_t)row * KDIM + v * H1 + col] = __float2bfloat16(o);
            }
        }
}

// ---------------------------------------------------------------------------
// Kernel C: relu(agg @ W3 + b3) . W4 -> atomicAdd into out.
// 256x256 tile, BK=32, 8 waves (2Mx4N), 512 thr.
// m201-faithful schedule: 4 LDS buffer pairs (128 KB), tile tt stages tile
// tt+3, single vmcnt(8) per tile -> loads in flight ~4 phases. Same-phase
// frag ds_read (no reg double-buffer). st_16x32 swizzle + XCD swizzle kept.
// ---------------------------------------------------------------------------
#define NT 128   // K-tiles of 32

__global__ __launch_bounds__(512, 2) void gemm3_kernel(
    const __hip_bfloat16* __restrict__ agg,   // [16384][4096]
    const __hip_bfloat16* __restrict__ w3t,   // [1024][4096]
    const float* __restrict__ b3, const float* __restrict__ W4,
    float* __restrict__ out) {
    // XCD swizzle (T1): XCD x gets bids [32x,32x+32) = 8 row-panels x 4 cols.
    const int bid = ((blockIdx.x & 7) << 5) + (blockIdx.x >> 3);
    const int brow = (bid >> 2) * 256;
    const int bcol = (bid & 3) * 256;
    const int t = threadIdx.x;
    const int lane = t & 63;
    const int wid = t >> 6;                   // 8 waves
    const int wm = wid >> 2, wn = wid & 3;    // 2 x 4, wave tile 128x64
    const int l15 = lane & 15, g = lane >> 4;

    // LDS: buffer pair p (p=0..3) at p*32768: A 16 KB @ +0, B 16 KB @ +16384
    __shared__ __align__(16) char smem[131072];

    // staging: chunk c -> dest byte c*16 (linear); source col pre-swizzled
    const int c0 = t, c1 = t + 512;
    const int r0 = c0 >> 2, r1 = c1 >> 2;
    const int col0 = ((c0 & 3) * 8) ^ ((r0 & 8) ? 16 : 0);
    const int col1 = ((c1 & 3) * 8) ^ ((r1 & 8) ? 16 : 0);
    const __hip_bfloat16* aS0 = agg + (size_t)(brow + r0) * KDIM + col0;
    const __hip_bfloat16* aS1 = agg + (size_t)(brow + r1) * KDIM + col1;
    const __hip_bfloat16* bS0 = w3t + (size_t)(bcol + r0) * KDIM + col0;
    const __hip_bfloat16* bS1 = w3t + (size_t)(bcol + r1) * KDIM + col1;

#define STAGE_A(p, kt) do { \
        gload_lds16(aS0 + (kt) * 32, smem + (p) * 32768 + c0 * 16); \
        gload_lds16(aS1 + (kt) * 32, smem + (p) * 32768 + c1 * 16); } while (0)
#define STAGE_B(p, kt) do { \
        gload_lds16(bS0 + (kt) * 32, smem + (p) * 32768 + 16384 + c0 * 16); \
        gload_lds16(bS1 + (kt) * 32, smem + (p) * 32768 + 16384 + c1 * 16); } while (0)

    // swizzled fragment reads (row&8 == l15&8 for all m/n)
    const int coff = (g * 16) ^ ((l15 & 8) ? 32 : 0);
    const int aBase = (wm * 128 + l15) * 64 + coff;
    const int bBase = 16384 + (wn * 64 + l15) * 64 + coff;

#define LDA(i, p) fa[i] = *(const short8*)(smem + (p) * 32768 + aBase + (i) * 1024)
#define LDB(i, p) fb[i] = *(const short8*)(smem + (p) * 32768 + bBase + (i) * 1024)

    short8 fa[8], fb[4];
    f32x4 acc[8][4];
#pragma unroll
    for (int m = 0; m < 8; m++)
#pragma unroll
        for (int n = 0; n < 4; n++) acc[m][n] = (f32x4){0.f, 0.f, 0.f, 0.f};

    // prologue: stage tiles 0,1,2; wait tile0 (own) -> barrier (cross-wave)
    STAGE_A(0, 0); STAGE_B(0, 0);
    STAGE_A(1, 1); STAGE_B(1, 1);
    STAGE_A(2, 2); STAGE_B(2, 2);
    asm volatile("s_waitcnt vmcnt(8)" ::: "memory");
    __builtin_amdgcn_s_barrier();

    // Phase A of tile tt: ds_read fa[0..3]+fb[0..3] (tile tt), stage A(tt+3),
    // barrier, lgkmcnt(0), 16 MFMA rows 0-3, barrier.
#define PH_A(p, DOSTAGE, kt3) do { \
        LDA(0, p); LDA(1, p); LDA(2, p); LDA(3, p); \
        LDB(0, p); LDB(1, p); LDB(2, p); LDB(3, p); \
        if (DOSTAGE) STAGE_A((kt3) & 3, kt3); \
        __builtin_amdgcn_s_barrier(); \
        asm volatile("s_waitcnt lgkmcnt(0)" ::: "memory"); \
        __builtin_amdgcn_sched_barrier(0); \
        __builtin_amdgcn_s_setprio(1); \
        _Pragma("unroll") \
        for (int mm = 0; mm < 4; mm++) \
            _Pragma("unroll") \
            for (int nn = 0; nn < 4; nn++) \
                acc[mm][nn] = __builtin_amdgcn_mfma_f32_16x16x32_bf16( \
                    fa[mm], fb[nn], acc[mm][nn], 0, 0, 0); \
        __builtin_amdgcn_s_setprio(0); \
        __builtin_amdgcn_s_barrier(); } while (0)

    // Phase B: ds_read fa[4..7], stage B(tt+3), vmcnt (tile tt+1 landed),
    // barrier, lgkmcnt(0), 16 MFMA rows 4-7, barrier.
#define PH_B(p, DOSTAGE, kt3, VMSTR) do { \
        LDA(4, p); LDA(5, p); LDA(6, p); LDA(7, p); \
        if (DOSTAGE) STAGE_B((kt3) & 3, kt3); \
        asm volatile(VMSTR ::: "memory"); \
        __builtin_amdgcn_s_barrier(); \
        asm volatile("s_waitcnt lgkmcnt(0)" ::: "memory"); \
        __builtin_amdgcn_sched_barrier(0); \
        __builtin_amdgcn_s_setprio(1); \
        _Pragma("unroll") \
        for (int mm = 0; mm < 4; mm++) \
            _Pragma("unroll") \
            for (int nn = 0; nn < 4; nn++) \
                acc[4 + mm][nn] = __builtin_amdgcn_mfma_f32_16x16x32_bf16( \
                    fa[4 + mm], fb[nn], acc[4 + mm][nn], 0, 0, 0); \
        __builtin_amdgcn_s_setprio(0); \
        __builtin_amdgcn_s_barrier(); } while (0)

    // main loop: tt = 0..123 (124 iters, unroll 4 -> p compile-time)
#pragma unroll 4
    for (int tt = 0; tt < NT - 4; ++tt) {
        const int p = tt & 3;
        PH_A(p, 1, tt + 3);
        PH_B(p, 1, tt + 3, "s_waitcnt vmcnt(8)");
    }
    // peeled tail: tt = 124 (stages tile 127), 125, 126, 127
    PH_A(0, 1, 127); PH_B(0, 1, 127, "s_waitcnt vmcnt(8)");
    PH_A(1, 0, 0);   PH_B(1, 0, 0, "s_waitcnt vmcnt(4)");
    PH_A(2, 0, 0);   PH_B(2, 0, 0, "s_waitcnt vmcnt(0)");
    PH_A(3, 0, 0);   PH_B(3, 0, 0, "s_waitcnt vmcnt(0)");

    // epilogue: bias+relu, dot W4, 16-lane reduce, atomicAdd per row
    float bias[4], w4v[4];
#pragma unroll
    for (int n = 0; n < 4; n++) {
        int col = bcol + wn * 64 + n * 16 + l15;
        bias[n] = b3[col];
        w4v[n] = W4[col];
    }
#pragma unroll
    for (int m = 0; m < 8; m++) {
        float pr0 = 0.f, pr1 = 0.f, pr2 = 0.f, pr3 = 0.f;
#pragma unroll
        for (int n = 0; n < 4; n++) {
            pr0 += fmaxf(acc[m][n][0] + bias[n], 0.f) * w4v[n];
            pr1 += fmaxf(acc[m][n][1] + bias[n], 0.f) * w4v[n];
            pr2 += fmaxf(acc[m][n][2] + bias[n], 0.f) * w4v[n];
            pr3 += fmaxf(acc[m][n][3] + bias[n], 0.f) * w4v[n];
        }
#pragma unroll
        for (int mask = 1; mask < 16; mask <<= 1) {
            pr0 += __shfl_xor(pr0, mask, 64);
            pr1 += __shfl_xor(pr1, mask, 64);
            pr2 += __shfl_xor(pr2, mask, 64);
            pr3 += __shfl_xor(pr3, mask, 64);
        }
        if (l15 == 0) {
            int row = brow + wm * 128 + m * 16 + g * 4;
            atomicAdd(&out[row + 0], pr0);
            atomicAdd(&out[row + 1], pr1);
            atomicAdd(&out[row + 2], pr2);
            atomicAdd(&out[row + 3], pr3);
        }
    }
}

// ---------------------------------------------------------------------------
extern "C" void kernel_launch(void* const* d_in, const int* in_sizes, int n_in,
                              void* d_out, int out_size, void* d_ws, size_t ws_size,
                              hipStream_t stream) {
    const float* inputs = (const float*)d_in[0];
    const float* W1 = (const float*)d_in[1];
    const float* b1 = (const float*)d_in[2];
    const float* W2 = (const float*)d_in[3];
    const float* b2 = (const float*)d_in[4];
    const float* imp = (const float*)d_in[5];
    const float* W3 = (const float*)d_in[6];
    const float* b3 = (const float*)d_in[7];
    const float* W4 = (const float*)d_in[8];
    const float* b4 = (const float*)d_in[9];
    float* out = (float*)d_out;

    char* ws = (char*)d_ws;
    const size_t agg_bytes  = (size_t)B_ROWS * KDIM * 2;
    const size_t w3t_bytes  = (size_t)H2 * KDIM * 2;
    const size_t w1b_bytes  = (size_t)NVARS * 64 * 40 * 2;
    const size_t w2b_bytes  = (size_t)NVARS * 64 * 72 * 2;

    __hip_bfloat16* agg = (__hip_bfloat16*)ws;
    __hip_bfloat16* w3t = (__hip_bfloat16*)(ws + agg_bytes);
    short* w1bh = (short*)(ws + agg_bytes + w3t_bytes);
    short* w1bl = (short*)(ws + agg_bytes + w3t_bytes + w1b_bytes);
    short* w2bh = (short*)(ws + agg_bytes + w3t_bytes + 2 * w1b_bytes);
    short* w2bl = (short*)(ws + agg_bytes + w3t_bytes + 2 * w1b_bytes + w2b_bytes);

    hipLaunchKernelGGL(convert_w3t_kernel, dim3(1024), dim3(256), 0, stream, W3, w3t);
    hipLaunchKernelGGL(prep_w12_kernel, dim3(NVARS), dim3(256), 0, stream,
                       W1, W2, w1bh, w1bl, w2bh, w2bl);
    hipLaunchKernelGGL(out_init_kernel, dim3(B_ROWS / 256), dim3(256), 0, stream, b4, out);
    hipLaunchKernelGGL(subnets_mfma_kernel, dim3(NVARS * (B_ROWS / 128)), dim3(256), 0, stream,
                       inputs, b1, b2, imp, w1bh, w1bl, w2bh, w2bl, agg);
    hipLaunchKernelGGL(gemm3_kernel, dim3((B_ROWS / 256) * (H2 / 256)), dim3(512), 0, stream,
                       agg, w3t, b3, W4, out);
}